// Round 22
// baseline (1098.269 us; speedup 1.0000x reference)
//
#include <hip/hip_runtime.h>

#define N_NODES 10000
#define N_EDGES 160000
#define NUM_FEAT 14
#define EDGE_DIM 4
#define DIM 64
#define HID 128
#define LAYERS 28

#define NPB 20
#define NLB (N_NODES / NPB)  // 500 blocks, exact
#define TPB 640              // 10 waves

// async global->LDS, 16B/lane: gsrc per-lane (base + lane*4 floats), lds_base
// wave-uniform; HW writes lds_base + lane*16.
__device__ __forceinline__ void stage16(const float* gsrc, float* lds_base) {
  __builtin_amdgcn_global_load_lds(
      (const __attribute__((address_space(1))) void*)gsrc,
      (__attribute__((address_space(3))) void*)lds_base, 16, 0, 0);
}

// ---------------- CSR build (prologue) ----------------

__global__ __launch_bounds__(256) void k_hist(const int* __restrict__ dst, int* __restrict__ cur) {
  int e = blockIdx.x * 256 + threadIdx.x;
  if (e < N_EDGES) atomicAdd(&cur[dst[e]], 1);
}

__global__ __launch_bounds__(256) void k_scan(int* __restrict__ cur, int* __restrict__ off) {
  __shared__ int part[256];
  int t = threadIdx.x;
  const int CH = 40;
  int base = t * CH;
  int s = 0;
  for (int i = 0; i < CH; i++) {
    int idx = base + i;
    if (idx < N_NODES) s += cur[idx];
  }
  part[t] = s;
  __syncthreads();
  for (int ofs = 1; ofs < 256; ofs <<= 1) {
    int tmp = (t >= ofs) ? part[t - ofs] : 0;
    __syncthreads();
    part[t] += tmp;
    __syncthreads();
  }
  int run = part[t] - s;
  for (int i = 0; i < CH; i++) {
    int idx = base + i;
    if (idx < N_NODES) {
      int d = cur[idx];
      off[idx] = run;
      cur[idx] = run;
      run += d;
    }
  }
  if (t == 255) off[N_NODES] = part[255];
}

__global__ __launch_bounds__(256) void k_scatter(const int* __restrict__ dst, int* __restrict__ cur,
                                                 int* __restrict__ eids) {
  int e = blockIdx.x * 256 + threadIdx.x;
  if (e < N_EDGES) {
    int p = atomicAdd(&cur[dst[e]], 1);
    eids[p] = e;
  }
}

// wave-per-node bitonic sort by edge id; gather src + eattr into slot order.
__global__ __launch_bounds__(256) void k_sortgather(
    const int* __restrict__ off, const int* __restrict__ eids,
    const int* __restrict__ src, const float4* __restrict__ eattr,
    int* __restrict__ src_s, float4* __restrict__ eattr_s) {
  int node = blockIdx.x * 4 + (threadIdx.x >> 6);
  int lane = threadIdx.x & 63;
  if (node >= N_NODES) return;
  int a = off[node];
  int d = off[node + 1] - a;
  if (d <= 64) {
    int key = (lane < d) ? eids[a + lane] : 0x7fffffff;
#pragma unroll
    for (int k = 2; k <= 64; k <<= 1) {
      for (int j = k >> 1; j > 0; j >>= 1) {
        int p = __shfl_xor(key, j);
        bool dirUp = ((lane & k) == 0);
        bool isLower = ((lane & j) == 0);
        key = ((isLower == dirUp) ? min(key, p) : max(key, p));
      }
    }
    if (lane < d) {
      src_s[a + lane] = src[key];
      eattr_s[a + lane] = eattr[key];
    }
  } else {
    for (int i = lane; i < d; i += 64) {
      int e = eids[a + i];
      int r = 0;
      for (int j = 0; j < d; j++) r += (eids[a + j] < e) ? 1 : 0;
      src_s[a + r] = src[e];
      eattr_s[a + r] = eattr[e];
    }
  }
}

// ---------------- node encoder ----------------

__global__ __launch_bounds__(256) void k_enc(const float* __restrict__ x, const float* __restrict__ Wn,
                                             const float* __restrict__ bn, float* __restrict__ hc,
                                             float* __restrict__ u) {
  int gid = blockIdx.x * 256 + threadIdx.x;
  if (gid >= N_NODES * DIM) return;
  int n = gid >> 6, j = gid & 63;
  float acc = bn[j];
#pragma unroll
  for (int k = 0; k < NUM_FEAT; k++) acc += x[n * NUM_FEAT + k] * Wn[k * DIM + j];
  hc[gid] = acc;
  u[gid] = acc;
}

// ---------------- edge aggregation helpers ----------------

__device__ __forceinline__ void load8(
    const float* __restrict__ uin, const float4* __restrict__ eattr_s,
    const int* __restrict__ src_s, int base, int lane,
    float we0, float we1, float we2, float we3, float be,
    float* uv, float* ep) {
#pragma unroll
  for (int j = 0; j < 8; j++) {
    int sn = src_s[base + j];            // s_load (uniform addr)
    uv[j] = uin[(sn << 6) + lane];       // sgpr-base gather (L2-resident)
    float4 ev = eattr_s[base + j];       // s_load_dwordx4 (uniform addr)
    ep[j] = be + ev.x * we0 + ev.y * we1 + ev.z * we2 + ev.w * we3;
  }
}

__device__ __forceinline__ void consume8(
    const float* uv, const float* ep, float tv,
    float& s0, float& s1, float& c0, float& c1) {
#pragma unroll
  for (int j = 0; j < 8; j++) {
    float msg = fmaxf(uv[j] + ep[j], 0.f) + 1e-7f;
    float e = __expf(msg * tv);
    if (j & 1) { s1 += e; c1 = fmaf(e, msg, c1); }
    else       { s0 += e; c0 = fmaf(e, msg, c0); }
  }
}

// guarded batch-8 remainder over slots [a+start, a+d): loads grouped before
// compute; rem is wave-uniform so guards are scalar branches.
__device__ __forceinline__ void edge_rest(
    int a, int start, int d, const float* __restrict__ uin,
    const float4* __restrict__ eattr_s, const int* __restrict__ src_s,
    int lane, float tv, float we0, float we1, float we2, float we3, float be,
    float& s0, float& s1, float& c0, float& c1) {
  for (int i = start; i < d; i += 8) {
    int rem = d - i;  // wave-uniform
    float uv[8], ep[8];
#pragma unroll
    for (int j = 0; j < 8; j++) {
      if (j < rem) {
        int sn = src_s[a + i + j];
        uv[j] = uin[(sn << 6) + lane];
        float4 ev = eattr_s[a + i + j];
        ep[j] = be + ev.x * we0 + ev.y * we1 + ev.z * we2 + ev.w * we3;
      }
    }
#pragma unroll
    for (int j = 0; j < 8; j++) {
      if (j < rem) {
        float msg = fmaxf(uv[j] + ep[j], 0.f) + 1e-7f;
        float e = __expf(msg * tv);
        if (j & 1) { s1 += e; c1 = fmaf(e, msg, c1); }
        else       { s0 += e; c0 = fmaf(e, msg, c0); }
      }
    }
  }
}

// Interleaved dual-node pipeline: the wave's two nodes (contiguous ids) run
// their batch-8 pipelines in lockstep -- consume(A_i), load(A_{i+1}),
// consume(B_i), load(B_{i+1}) -- so each load's latency hides under the OTHER
// node's compute. Same 32-float live set as R18's single-node prefetch.
// Leftover batches + tails use the guarded pattern. Max-free softmax.
__device__ __forceinline__ void edge_pair(
    int gn0, const float* __restrict__ uin, const float4* __restrict__ eattr_s,
    const int* __restrict__ src_s, const int* __restrict__ off,
    int lane, float tv, float we0, float we1, float we2, float we3, float be,
    float& h0, float& h1) {
  int a0 = off[gn0], a1 = off[gn0 + 1], a2 = off[gn0 + 2];  // scalar
  int dA = a1 - a0, dB = a2 - a1;
  float unA = uin[(gn0 << 6) + lane];
  float unB = uin[((gn0 + 1) << 6) + lane];
  float sA0 = 0.f, sA1 = 0.f, cA0 = 0.f, cA1 = 0.f;
  float sB0 = 0.f, sB1 = 0.f, cB0 = 0.f, cB1 = 0.f;
  int nbm = (dA < dB ? dA : dB) & ~7;  // shared full-batch count (uniform)
  float uvA[8], epA[8], uvB[8], epB[8];
  if (nbm > 0) {
    load8(uin, eattr_s, src_s, a0, lane, we0, we1, we2, we3, be, uvA, epA);
    load8(uin, eattr_s, src_s, a1, lane, we0, we1, we2, we3, be, uvB, epB);
    for (int i = 0; i < nbm; i += 8) {
      const bool more = (i + 8) < nbm;  // wave-uniform
      consume8(uvA, epA, tv, sA0, sA1, cA0, cA1);
      if (more)
        load8(uin, eattr_s, src_s, a0 + i + 8, lane, we0, we1, we2, we3, be, uvA, epA);
      consume8(uvB, epB, tv, sB0, sB1, cB0, cB1);
      if (more)
        load8(uin, eattr_s, src_s, a1 + i + 8, lane, we0, we1, we2, we3, be, uvB, epB);
    }
  }
  // leftover full batches + tail for each node (one of these is usually tiny)
  edge_rest(a0, nbm, dA, uin, eattr_s, src_s, lane, tv, we0, we1, we2, we3, be,
            sA0, sA1, cA0, cA1);
  edge_rest(a1, nbm, dB, uin, eattr_s, src_s, lane, tv, we0, we1, we2, we3, be,
            sB0, sB1, cB0, cB1);
  h0 = (cA0 + cA1) / (sA0 + sA1 + 1e-16f) + unA;
  h1 = (cB0 + cB1) / (sB0 + sB1 + 1e-16f) + unB;
}

// ---------------- fused layer: edge-agg + MLP, one dispatch, one barrier ----------------
// R18-proven structure: 640 threads (10 waves), 20 nodes/block, 500 blocks,
// 74KB LDS -> 2 blocks/CU (~20 waves/CU). Wave owns 2 nodes end-to-end.

__global__ __launch_bounds__(640, 5) void k_layer(
    const float* __restrict__ uin, float* __restrict__ hc, float* __restrict__ uout,
    const float4* __restrict__ eattr_s, const int* __restrict__ src_s,
    const int* __restrict__ off, const float* __restrict__ tptr, int layer,
    const float* __restrict__ W_edge, const float* __restrict__ b_edge,
    const float* __restrict__ W1, const float* __restrict__ b1,
    const float* __restrict__ g1, const float* __restrict__ be1,
    const float* __restrict__ W2, const float* __restrict__ b2,
    const float* __restrict__ lng, const float* __restrict__ lnb,
    int addRes, int writeU) {
  __shared__ float sW1[64 * 128];   // 32KB [k][j]
  __shared__ float sW2[128 * 64];   // 32KB [k][i]
  __shared__ float sHZ[10][256];    // 10KB union: h interleaved [0..128), z [0..256)

  const int tid = threadIdx.x;
  const int lane = tid & 63;
  const int wv = tid >> 6;  // 0..9
  const int nbase = blockIdx.x * NPB;

  // ---- stage weights (fire-and-forget; drained by the barrier below) ----
  for (int c = wv; c < 32; c += 10) {
    stage16(W1 + c * 256 + lane * 4, sW1 + c * 256);
    stage16(W2 + c * 256 + lane * 4, sW2 + c * 256);
  }

  // ---- edge aggregation: 2 nodes per wave, interleaved dual pipeline ----
  {
    float tv = tptr[layer];
    float we0 = W_edge[lane], we1 = W_edge[64 + lane], we2 = W_edge[128 + lane],
          we3 = W_edge[192 + lane];
    float be = b_edge[lane];
    int gn0 = __builtin_amdgcn_readfirstlane(nbase + wv * 2);
    float h0, h1;
    edge_pair(gn0, uin, eattr_s, src_s, off, lane, tv, we0, we1, we2, we3, be, h0, h1);
    *((float2*)&sHZ[wv][lane * 2]) = make_float2(h0, h1);
  }
  __syncthreads();  // drains global_load_lds (weights ready); sHZ wave-private

  const int gn0 = nbase + wv * 2;
  const int gn1 = gn0 + 1;

  // ---- GEMM1: cols j0=2*lane, j0+1; 2 nodes ----
  int j0 = 2 * lane;
  float2 b1v = *((const float2*)&b1[j0]);
  float a00 = b1v.x, a01 = b1v.y, a10 = b1v.x, a11 = b1v.y;
#pragma unroll 8
  for (int k = 0; k < 64; k++) {
    float2 hp = *((float2*)&sHZ[wv][k * 2]);
    float2 wp = *((float2*)&sW1[k * 128 + j0]);
    a00 += hp.x * wp.x; a01 += hp.x * wp.y;
    a10 += hp.y * wp.x; a11 += hp.y * wp.y;
  }

  // ---- LN1 (over 128) via shfl; z overwrites sHZ (same wave, dep-ordered) ----
  {
    float2 gv = *((const float2*)&g1[j0]);
    float2 bev = *((const float2*)&be1[j0]);
    float s0 = a00 + a01, q0 = a00 * a00 + a01 * a01;
    float s1 = a10 + a11, q1 = a10 * a10 + a11 * a11;
#pragma unroll
    for (int o = 32; o; o >>= 1) {
      s0 += __shfl_xor(s0, o); q0 += __shfl_xor(q0, o);
      s1 += __shfl_xor(s1, o); q1 += __shfl_xor(q1, o);
    }
    float mu0 = s0 * (1.f / 128.f), mu1 = s1 * (1.f / 128.f);
    float rs0 = rsqrtf(q0 * (1.f / 128.f) - mu0 * mu0 + 1e-5f);
    float rs1 = rsqrtf(q1 * (1.f / 128.f) - mu1 * mu1 + 1e-5f);
    float4 zv;
    zv.x = fmaxf((a00 - mu0) * rs0 * gv.x + bev.x, 0.f);
    zv.y = fmaxf((a10 - mu1) * rs1 * gv.x + bev.x, 0.f);
    zv.z = fmaxf((a01 - mu0) * rs0 * gv.y + bev.y, 0.f);
    zv.w = fmaxf((a11 - mu1) * rs1 * gv.y + bev.y, 0.f);
    *((float4*)&sHZ[wv][4 * lane]) = zv;
  }

  // ---- GEMM2: col i=lane; 2 nodes ----
  float bo = b2[lane];
  float o0 = bo, o1 = bo;
#pragma unroll 8
  for (int k = 0; k < 128; k++) {
    float2 zp = *((float2*)&sHZ[wv][k * 2]);
    float wv2 = sW2[k * 64 + lane];
    o0 += zp.x * wv2;
    o1 += zp.y * wv2;
  }

  // ---- residual + hc write ----
  float r0 = addRes ? hc[gn0 * 64 + lane] : 0.f;
  float r1 = addRes ? hc[gn1 * 64 + lane] : 0.f;
  float hcn0 = o0 + r0, hcn1 = o1 + r1;
  hc[gn0 * 64 + lane] = hcn0;
  hc[gn1 * 64 + lane] = hcn1;

  // ---- next-layer pre-LN: uout = relu(LN(hc)) ----
  if (writeU) {
    float lg_ = lng[lane], lb_ = lnb[lane];
    float s0 = hcn0, q0 = hcn0 * hcn0;
    float s1 = hcn1, q1 = hcn1 * hcn1;
#pragma unroll
    for (int o = 32; o; o >>= 1) {
      s0 += __shfl_xor(s0, o); q0 += __shfl_xor(q0, o);
      s1 += __shfl_xor(s1, o); q1 += __shfl_xor(q1, o);
    }
    float mu0 = s0 * (1.f / 64.f), mu1 = s1 * (1.f / 64.f);
    float rs0 = rsqrtf(q0 * (1.f / 64.f) - mu0 * mu0 + 1e-5f);
    float rs1 = rsqrtf(q1 * (1.f / 64.f) - mu1 * mu1 + 1e-5f);
    uout[gn0 * 64 + lane] = fmaxf((hcn0 - mu0) * rs0 * lg_ + lb_, 0.f);
    uout[gn1 * 64 + lane] = fmaxf((hcn1 - mu1) * rs1 * lg_ + lb_, 0.f);
  }
}

// ---------------- final: out = relu(LN(hc, g0, b0)) @ W_out + b_out ----------------

__global__ __launch_bounds__(256) void k_final(const float* __restrict__ hc, const float* __restrict__ g,
                                               const float* __restrict__ bptr, const float* __restrict__ Wout,
                                               const float* __restrict__ bout, float* __restrict__ out) {
  __shared__ float sW[DIM * DIM];
  int tid = threadIdx.x;
  for (int i = tid; i < 1024; i += 256) ((float4*)sW)[i] = ((const float4*)Wout)[i];
  __syncthreads();
  int lane = tid & 63, w = tid >> 6;
  int n = blockIdx.x * 4 + w;
  if (n >= N_NODES) return;
  float v = hc[n * 64 + lane];
  float s = v, q = v * v;
#pragma unroll
  for (int o = 32; o; o >>= 1) { s += __shfl_xor(s, o); q += __shfl_xor(q, o); }
  float mu = s * (1.f / 64.f);
  float var = q * (1.f / 64.f) - mu * mu;
  float rs = rsqrtf(var + 1e-5f);
  float z = fmaxf((v - mu) * rs * g[lane] + bptr[lane], 0.f);
  float acc = bout[lane];
  for (int k = 0; k < 64; k++) {
    float zk = __shfl(z, k);
    acc += zk * sW[k * 64 + lane];
  }
  out[n * 64 + lane] = acc;
}

// ---------------- host ----------------

extern "C" void kernel_launch(void* const* d_in, const int* in_sizes, int n_in,
                              void* d_out, int out_size, void* d_ws, size_t ws_size,
                              hipStream_t stream) {
  const float* x        = (const float*)d_in[0];
  const float* eattr    = (const float*)d_in[1];
  const int*   src      = (const int*)d_in[2];
  const int*   dst      = (const int*)d_in[3];
  const float* W_node   = (const float*)d_in[4];
  const float* b_node   = (const float*)d_in[5];
  const float* W_edge   = (const float*)d_in[6];
  const float* b_edge   = (const float*)d_in[7];
  const float* t        = (const float*)d_in[8];
  const float* W1       = (const float*)d_in[9];
  const float* b1       = (const float*)d_in[10];
  const float* g1       = (const float*)d_in[11];
  const float* be1      = (const float*)d_in[12];
  const float* W2       = (const float*)d_in[13];
  const float* b2       = (const float*)d_in[14];
  const float* ln_g     = (const float*)d_in[15];
  const float* ln_b     = (const float*)d_in[16];
  const float* W_out    = (const float*)d_in[17];
  const float* b_out    = (const float*)d_in[18];
  float* out = (float*)d_out;

  char* w = (char*)d_ws;
  float* uA      = (float*)w;  w += (size_t)N_NODES * 64 * 4;
  float* uB      = (float*)w;  w += (size_t)N_NODES * 64 * 4;
  float* hcb     = (float*)w;  w += (size_t)N_NODES * 64 * 4;
  int* off       = (int*)w;    w += (size_t)(N_NODES + 1) * 4;
  int* cur       = (int*)w;    w += (size_t)N_NODES * 4;
  int* eids      = (int*)w;    w += (size_t)N_EDGES * 4;
  int* src_s     = (int*)w;    w += (size_t)N_EDGES * 4;
  float4* eattr_s = (float4*)w; w += (size_t)N_EDGES * 16;

  hipMemsetAsync(cur, 0, (size_t)N_NODES * 4, stream);
  k_hist<<<(N_EDGES + 255) / 256, 256, 0, stream>>>(dst, cur);
  k_scan<<<1, 256, 0, stream>>>(cur, off);
  k_scatter<<<(N_EDGES + 255) / 256, 256, 0, stream>>>(dst, cur, eids);
  k_sortgather<<<(N_NODES + 3) / 4, 256, 0, stream>>>(off, eids, src, (const float4*)eattr,
                                                      src_s, eattr_s);

  k_enc<<<(N_NODES * 64 + 255) / 256, 256, 0, stream>>>(x, W_node, b_node, hcb, uA);

  for (int l = 0; l < LAYERS; l++) {
    const float* uin = (l & 1) ? uB : uA;
    float* uo        = (l & 1) ? uA : uB;
    int nxt = (l + 1 < LAYERS) ? (l + 1) : 0;  // unused when writeU=0
    k_layer<<<NLB, TPB, 0, stream>>>(uin, hcb, uo, (const float4*)eattr_s, src_s, off, t, l,
                                     W_edge, b_edge,
                                     W1 + (size_t)l * DIM * HID, b1 + (size_t)l * HID,
                                     g1 + (size_t)l * HID, be1 + (size_t)l * HID,
                                     W2 + (size_t)l * HID * DIM, b2 + (size_t)l * DIM,
                                     ln_g + (size_t)nxt * DIM, ln_b + (size_t)nxt * DIM,
                                     (l > 0) ? 1 : 0, (l < LAYERS - 1) ? 1 : 0);
  }

  k_final<<<(N_NODES + 3) / 4, 256, 0, stream>>>(hcb, ln_g, ln_b, W_out, b_out, out);
}

// Round 23
// 836.668 us; speedup vs baseline: 1.3127x; 1.3127x over previous
//
#include <hip/hip_runtime.h>

#define N_NODES 10000
#define N_EDGES 160000
#define NUM_FEAT 14
#define EDGE_DIM 4
#define DIM 64
#define HID 128
#define LAYERS 28

#define NPB 8
#define NLB (N_NODES / NPB)  // 1250 blocks, exact
#define TPB 512              // 8 waves, 1 node/wave

// async global->LDS, 16B/lane: gsrc per-lane (base + lane*4 floats), lds_base
// wave-uniform; HW writes lds_base + lane*16.
__device__ __forceinline__ void stage16(const float* gsrc, float* lds_base) {
  __builtin_amdgcn_global_load_lds(
      (const __attribute__((address_space(1))) void*)gsrc,
      (__attribute__((address_space(3))) void*)lds_base, 16, 0, 0);
}

// ---------------- CSR build (prologue) ----------------

__global__ __launch_bounds__(256) void k_hist(const int* __restrict__ dst, int* __restrict__ cur) {
  int e = blockIdx.x * 256 + threadIdx.x;
  if (e < N_EDGES) atomicAdd(&cur[dst[e]], 1);
}

__global__ __launch_bounds__(256) void k_scan(int* __restrict__ cur, int* __restrict__ off) {
  __shared__ int part[256];
  int t = threadIdx.x;
  const int CH = 40;
  int base = t * CH;
  int s = 0;
  for (int i = 0; i < CH; i++) {
    int idx = base + i;
    if (idx < N_NODES) s += cur[idx];
  }
  part[t] = s;
  __syncthreads();
  for (int ofs = 1; ofs < 256; ofs <<= 1) {
    int tmp = (t >= ofs) ? part[t - ofs] : 0;
    __syncthreads();
    part[t] += tmp;
    __syncthreads();
  }
  int run = part[t] - s;
  for (int i = 0; i < CH; i++) {
    int idx = base + i;
    if (idx < N_NODES) {
      int d = cur[idx];
      off[idx] = run;
      cur[idx] = run;
      run += d;
    }
  }
  if (t == 255) off[N_NODES] = part[255];
}

__global__ __launch_bounds__(256) void k_scatter(const int* __restrict__ dst, int* __restrict__ cur,
                                                 int* __restrict__ eids) {
  int e = blockIdx.x * 256 + threadIdx.x;
  if (e < N_EDGES) {
    int p = atomicAdd(&cur[dst[e]], 1);
    eids[p] = e;
  }
}

// wave-per-node bitonic sort by edge id; gather src + eattr into slot order.
__global__ __launch_bounds__(256) void k_sortgather(
    const int* __restrict__ off, const int* __restrict__ eids,
    const int* __restrict__ src, const float4* __restrict__ eattr,
    int* __restrict__ src_s, float4* __restrict__ eattr_s) {
  int node = blockIdx.x * 4 + (threadIdx.x >> 6);
  int lane = threadIdx.x & 63;
  if (node >= N_NODES) return;
  int a = off[node];
  int d = off[node + 1] - a;
  if (d <= 64) {
    int key = (lane < d) ? eids[a + lane] : 0x7fffffff;
#pragma unroll
    for (int k = 2; k <= 64; k <<= 1) {
      for (int j = k >> 1; j > 0; j >>= 1) {
        int p = __shfl_xor(key, j);
        bool dirUp = ((lane & k) == 0);
        bool isLower = ((lane & j) == 0);
        key = ((isLower == dirUp) ? min(key, p) : max(key, p));
      }
    }
    if (lane < d) {
      src_s[a + lane] = src[key];
      eattr_s[a + lane] = eattr[key];
    }
  } else {
    for (int i = lane; i < d; i += 64) {
      int e = eids[a + i];
      int r = 0;
      for (int j = 0; j < d; j++) r += (eids[a + j] < e) ? 1 : 0;
      src_s[a + r] = src[e];
      eattr_s[a + r] = eattr[e];
    }
  }
}

// ---------------- node encoder ----------------

__global__ __launch_bounds__(256) void k_enc(const float* __restrict__ x, const float* __restrict__ Wn,
                                             const float* __restrict__ bn, float* __restrict__ hc,
                                             float* __restrict__ u) {
  int gid = blockIdx.x * 256 + threadIdx.x;
  if (gid >= N_NODES * DIM) return;
  int n = gid >> 6, j = gid & 63;
  float acc = bn[j];
#pragma unroll
  for (int k = 0; k < NUM_FEAT; k++) acc += x[n * NUM_FEAT + k] * Wn[k * DIM + j];
  hc[gid] = acc;
  u[gid] = acc;
}

// R18-proven per-node edge aggregation: software-pipelined batch-8 (one batch
// prefetch), max-free softmax, ea recomputed from wave-uniform eattr_s
// (s_load_dwordx4) + 4 FMAs. Per-lane memory = L2-resident u-row gather.
__device__ __forceinline__ float edge_node(
    int gn, const float* __restrict__ uin, const float4* __restrict__ eattr_s,
    const int* __restrict__ src_s, const int* __restrict__ off,
    int lane, float tv, float we0, float we1, float we2, float we3, float be) {
  int a = off[gn], d = off[gn + 1] - a;  // scalar (gn wave-uniform)
  float un = uin[(gn << 6) + lane];
  float s0 = 0.f, s1 = 0.f, ac0 = 0.f, ac1 = 0.f;
  int nb = d & ~7;
  float uv[8], ep[8];
  if (nb > 0) {
#pragma unroll
    for (int j = 0; j < 8; j++) {
      int sn = src_s[a + j];              // s_load (uniform addr)
      uv[j] = uin[(sn << 6) + lane];      // sgpr-base gather (L2-resident)
      float4 ev = eattr_s[a + j];         // s_load_dwordx4 (uniform addr)
      ep[j] = be + ev.x * we0 + ev.y * we1 + ev.z * we2 + ev.w * we3;
    }
  }
  for (int i = 0; i < nb; i += 8) {
    float uvn[8], epn[8];
    const bool more = (i + 8) < nb;       // wave-uniform
    if (more) {
#pragma unroll
      for (int j = 0; j < 8; j++) {       // issue NEXT batch's loads first
        int sn = src_s[a + i + 8 + j];
        uvn[j] = uin[(sn << 6) + lane];
        float4 ev = eattr_s[a + i + 8 + j];
        epn[j] = be + ev.x * we0 + ev.y * we1 + ev.z * we2 + ev.w * we3;
      }
    }
#pragma unroll
    for (int j = 0; j < 8; j++) {         // consume CURRENT batch
      float msg = fmaxf(uv[j] + ep[j], 0.f) + 1e-7f;
      float e = __expf(msg * tv);
      if (j & 1) { s1 += e; ac1 = fmaf(e, msg, ac1); }
      else       { s0 += e; ac0 = fmaf(e, msg, ac0); }
    }
    if (more) {
#pragma unroll
      for (int j = 0; j < 8; j++) { uv[j] = uvn[j]; ep[j] = epn[j]; }
    }
  }
  for (int i = nb; i < d; i++) {          // tail (< 8 edges)
    int sn = src_s[a + i];
    float4 ev = eattr_s[a + i];
    float epp = be + ev.x * we0 + ev.y * we1 + ev.z * we2 + ev.w * we3;
    float msg = fmaxf(uin[(sn << 6) + lane] + epp, 0.f) + 1e-7f;
    float e = __expf(msg * tv);
    s0 += e;
    ac0 = fmaf(e, msg, ac0);
  }
  return (ac0 + ac1) / (s0 + s1 + 1e-16f) + un;
}

// ---------------- fused layer: 1 node/wave, 32 waves/CU ----------------
// 512 threads (8 waves), 8 nodes/block, 1250 blocks. LDS = W1 (32KB) + per-wave
// h/z union (4KB) = 36KB -> 4 blocks/CU = 32 waves/CU (hardware thread cap),
// 1.6x R18's latency hiding, and each wave has HALF the serial edge work.
// GEMM2 reads W2 directly from global: W2[k*64+lane] is coalesced 256B/iter
// and W2 (32KB) is L1-resident. sHZ is wave-private: h [0..64) during GEMM1,
// z [0..128) after (same-wave dep-ordered overwrite).

__global__ __launch_bounds__(512, 8) void k_layer(
    const float* __restrict__ uin, float* __restrict__ hc, float* __restrict__ uout,
    const float4* __restrict__ eattr_s, const int* __restrict__ src_s,
    const int* __restrict__ off, const float* __restrict__ tptr, int layer,
    const float* __restrict__ W_edge, const float* __restrict__ b_edge,
    const float* __restrict__ W1, const float* __restrict__ b1,
    const float* __restrict__ g1, const float* __restrict__ be1,
    const float* __restrict__ W2, const float* __restrict__ b2,
    const float* __restrict__ lng, const float* __restrict__ lnb,
    int addRes, int writeU) {
  __shared__ float sW1[64 * 128];   // 32KB [k][j]
  __shared__ float sHZ[8][128];     // 4KB per-wave union: h [0..64), z [0..128)

  const int tid = threadIdx.x;
  const int lane = tid & 63;
  const int wv = tid >> 6;  // 0..7
  const int gn = __builtin_amdgcn_readfirstlane(blockIdx.x * NPB + wv);

  // ---- stage W1 (fire-and-forget; drained by the barrier below) ----
  for (int c = wv; c < 32; c += 8) {
    stage16(W1 + c * 256 + lane * 4, sW1 + c * 256);
  }

  // ---- edge aggregation: ONE node per wave (half R18's serial chain) ----
  {
    float tv = tptr[layer];
    float we0 = W_edge[lane], we1 = W_edge[64 + lane], we2 = W_edge[128 + lane],
          we3 = W_edge[192 + lane];
    float be = b_edge[lane];
    float h = edge_node(gn, uin, eattr_s, src_s, off, lane, tv, we0, we1, we2, we3, be);
    sHZ[wv][lane] = h;  // h[feat], wave-private
  }
  __syncthreads();  // drains global_load_lds (W1 ready); sHZ wave-private

  // ---- GEMM1: cols j0=2*lane, j0+1; h broadcast from LDS ----
  int j0 = 2 * lane;
  float2 b1v = *((const float2*)&b1[j0]);
  float a0 = b1v.x, a1 = b1v.y;
#pragma unroll 8
  for (int k = 0; k < 64; k++) {
    float h = sHZ[wv][k];                       // wave-uniform broadcast
    float2 wp = *((float2*)&sW1[k * 128 + j0]); // conflict-free b64
    a0 = fmaf(h, wp.x, a0);
    a1 = fmaf(h, wp.y, a1);
  }

  // ---- LN1 (over 128) via shfl; z overwrites sHZ (same wave, dep-ordered) ----
  {
    float2 gv = *((const float2*)&g1[j0]);
    float2 bev = *((const float2*)&be1[j0]);
    float s = a0 + a1, q = a0 * a0 + a1 * a1;
#pragma unroll
    for (int o = 32; o; o >>= 1) { s += __shfl_xor(s, o); q += __shfl_xor(q, o); }
    float mu = s * (1.f / 128.f);
    float rs = rsqrtf(q * (1.f / 128.f) - mu * mu + 1e-5f);
    float2 zv;
    zv.x = fmaxf((a0 - mu) * rs * gv.x + bev.x, 0.f);
    zv.y = fmaxf((a1 - mu) * rs * gv.y + bev.y, 0.f);
    *((float2*)&sHZ[wv][j0]) = zv;  // z[0..128), wave-private
  }

  // ---- GEMM2: col i=lane; z broadcast from LDS, W2 from global (L1) ----
  float o = b2[lane];
#pragma unroll 8
  for (int k = 0; k < 128; k++) {
    float z = sHZ[wv][k];            // wave-uniform broadcast
    o = fmaf(z, W2[k * 64 + lane], o);  // coalesced, L1-resident
  }

  // ---- residual + hc write ----
  float r = addRes ? hc[gn * 64 + lane] : 0.f;
  float hcn = o + r;
  hc[gn * 64 + lane] = hcn;

  // ---- next-layer pre-LN: uout = relu(LN(hc)) ----
  if (writeU) {
    float lg_ = lng[lane], lb_ = lnb[lane];
    float s = hcn, q = hcn * hcn;
#pragma unroll
    for (int o2 = 32; o2; o2 >>= 1) { s += __shfl_xor(s, o2); q += __shfl_xor(q, o2); }
    float mu = s * (1.f / 64.f);
    float rs = rsqrtf(q * (1.f / 64.f) - mu * mu + 1e-5f);
    uout[gn * 64 + lane] = fmaxf((hcn - mu) * rs * lg_ + lb_, 0.f);
  }
}

// ---------------- final: out = relu(LN(hc, g0, b0)) @ W_out + b_out ----------------

__global__ __launch_bounds__(256) void k_final(const float* __restrict__ hc, const float* __restrict__ g,
                                               const float* __restrict__ bptr, const float* __restrict__ Wout,
                                               const float* __restrict__ bout, float* __restrict__ out) {
  __shared__ float sW[DIM * DIM];
  int tid = threadIdx.x;
  for (int i = tid; i < 1024; i += 256) ((float4*)sW)[i] = ((const float4*)Wout)[i];
  __syncthreads();
  int lane = tid & 63, w = tid >> 6;
  int n = blockIdx.x * 4 + w;
  if (n >= N_NODES) return;
  float v = hc[n * 64 + lane];
  float s = v, q = v * v;
#pragma unroll
  for (int o = 32; o; o >>= 1) { s += __shfl_xor(s, o); q += __shfl_xor(q, o); }
  float mu = s * (1.f / 64.f);
  float var = q * (1.f / 64.f) - mu * mu;
  float rs = rsqrtf(var + 1e-5f);
  float z = fmaxf((v - mu) * rs * g[lane] + bptr[lane], 0.f);
  float acc = bout[lane];
  for (int k = 0; k < 64; k++) {
    float zk = __shfl(z, k);
    acc += zk * sW[k * 64 + lane];
  }
  out[n * 64 + lane] = acc;
}

// ---------------- host ----------------

extern "C" void kernel_launch(void* const* d_in, const int* in_sizes, int n_in,
                              void* d_out, int out_size, void* d_ws, size_t ws_size,
                              hipStream_t stream) {
  const float* x        = (const float*)d_in[0];
  const float* eattr    = (const float*)d_in[1];
  const int*   src      = (const int*)d_in[2];
  const int*   dst      = (const int*)d_in[3];
  const float* W_node   = (const float*)d_in[4];
  const float* b_node   = (const float*)d_in[5];
  const float* W_edge   = (const float*)d_in[6];
  const float* b_edge   = (const float*)d_in[7];
  const float* t        = (const float*)d_in[8];
  const float* W1       = (const float*)d_in[9];
  const float* b1       = (const float*)d_in[10];
  const float* g1       = (const float*)d_in[11];
  const float* be1      = (const float*)d_in[12];
  const float* W2       = (const float*)d_in[13];
  const float* b2       = (const float*)d_in[14];
  const float* ln_g     = (const float*)d_in[15];
  const float* ln_b     = (const float*)d_in[16];
  const float* W_out    = (const float*)d_in[17];
  const float* b_out    = (const float*)d_in[18];
  float* out = (float*)d_out;

  char* w = (char*)d_ws;
  float* uA      = (float*)w;  w += (size_t)N_NODES * 64 * 4;
  float* uB      = (float*)w;  w += (size_t)N_NODES * 64 * 4;
  float* hcb     = (float*)w;  w += (size_t)N_NODES * 64 * 4;
  int* off       = (int*)w;    w += (size_t)(N_NODES + 1) * 4;
  int* cur       = (int*)w;    w += (size_t)N_NODES * 4;
  int* eids      = (int*)w;    w += (size_t)N_EDGES * 4;
  int* src_s     = (int*)w;    w += (size_t)N_EDGES * 4;
  float4* eattr_s = (float4*)w; w += (size_t)N_EDGES * 16;

  hipMemsetAsync(cur, 0, (size_t)N_NODES * 4, stream);
  k_hist<<<(N_EDGES + 255) / 256, 256, 0, stream>>>(dst, cur);
  k_scan<<<1, 256, 0, stream>>>(cur, off);
  k_scatter<<<(N_EDGES + 255) / 256, 256, 0, stream>>>(dst, cur, eids);
  k_sortgather<<<(N_NODES + 3) / 4, 256, 0, stream>>>(off, eids, src, (const float4*)eattr,
                                                      src_s, eattr_s);

  k_enc<<<(N_NODES * 64 + 255) / 256, 256, 0, stream>>>(x, W_node, b_node, hcb, uA);

  for (int l = 0; l < LAYERS; l++) {
    const float* uin = (l & 1) ? uB : uA;
    float* uo        = (l & 1) ? uA : uB;
    int nxt = (l + 1 < LAYERS) ? (l + 1) : 0;  // unused when writeU=0
    k_layer<<<NLB, TPB, 0, stream>>>(uin, hcb, uo, (const float4*)eattr_s, src_s, off, t, l,
                                     W_edge, b_edge,
                                     W1 + (size_t)l * DIM * HID, b1 + (size_t)l * HID,
                                     g1 + (size_t)l * HID, be1 + (size_t)l * HID,
                                     W2 + (size_t)l * HID * DIM, b2 + (size_t)l * DIM,
                                     ln_g + (size_t)nxt * DIM, ln_b + (size_t)nxt * DIM,
                                     (l > 0) ? 1 : 0, (l < LAYERS - 1) ? 1 : 0);
  }

  k_final<<<(N_NODES + 3) / 4, 256, 0, stream>>>(hcb, ln_g, ln_b, W_out, b_out, out);
}